// Round 30
// baseline (490.116 us; speedup 1.0000x reference)
//

#include <hip/hip_runtime.h>
#include <hip/hip_bf16.h>

#define CIN   1024
#define FEATN 64
#define HH    48
#define WW    160
#define DDN   48
#define EPSV  1e-5f
#define NTAP  27
#define WSLAB 162             // wIdx 0..161 covers w' = -1..160

typedef __attribute__((ext_vector_type(8))) short bf16x8;
typedef __attribute__((ext_vector_type(4))) float f32x4;
typedef __attribute__((ext_vector_type(4))) unsigned short u16x4;

static __device__ __forceinline__ unsigned short f2bf(float x) {
    __hip_bfloat16 h = __float2bfloat16(x);
    return *(unsigned short*)&h;
}

// ---------------------------------------------------------------------------
// Pack conv3a weights: Wb[o][tap][ci128] bf16 from w3a[o][ci][tap] f32
// ---------------------------------------------------------------------------
__global__ void CostVolume_6201932775918_packw(const float* w3, unsigned short* Wb)
{
    int i = (int)(blockIdx.x * 256 + threadIdx.x);
    if (i >= 64 * NTAP * 128) return;
    int ci  = i & 127;
    int tap = (i >> 7) % NTAP;
    int o   = i / (NTAP * 128);
    Wb[i] = f2bf(w3[o * 3456 + ci * 27 + tap]);
}

// ---------------------------------------------------------------------------
// Pack conv3b weights: Wb2[o][tap][ci64] bf16 from w3b[o][ci][tap] f32
// ---------------------------------------------------------------------------
__global__ void CostVolume_6201932775918_packw2(const float* w3, unsigned short* Wb2)
{
    int i = (int)(blockIdx.x * 256 + threadIdx.x);
    if (i >= 64 * NTAP * 64) return;
    int ci  = i & 63;
    int tap = (i >> 6) % NTAP;
    int o   = i / (NTAP * 64);
    Wb2[i] = f2bf(w3[o * 1728 + ci * 27 + tap]);
}

// ---------------------------------------------------------------------------
// down_sample: 1x1 conv + BN + ReLU -> bf16 CHANNEL-LAST Lt/Rt [h*W+w][ci]
// ---------------------------------------------------------------------------
__global__ void CostVolume_6201932775918_ds(
    const float* Lf, const float* Rf,
    const float* dsw, const float* dsb,
    const float* g2, const float* b2, const float* m2, const float* v2,
    unsigned short* outL, unsigned short* outR)
{
    const float* in = (blockIdx.y == 0) ? Lf : Rf;
    unsigned short* out = (blockIdx.y == 0) ? outL : outR;
    const int t    = (int)threadIdx.x;
    const int pos0 = (int)blockIdx.x * 64;
    const int oq   = t & 15;            // o = 4*oq + k
    const int pq   = t >> 4;            // pos = pos0 + pq*4 + j

    __shared__ float chunk[64 * 64];

    float acc[4][4];
    #pragma unroll
    for (int k = 0; k < 4; ++k)
        #pragma unroll
        for (int j = 0; j < 4; ++j) acc[k][j] = 0.f;

    for (int cc = 0; cc < 16; ++cc) {
        __syncthreads();
        #pragma unroll
        for (int i = 0; i < 16; ++i) {
            int idx = i * 256 + t;
            int cl = idx >> 6;
            int p  = idx & 63;
            chunk[cl * 64 + p] = in[(cc * 64 + cl) * (HH * WW) + pos0 + p];
        }
        __syncthreads();
        for (int cl = 0; cl < 64; ++cl) {
            int c = cc * 64 + cl;
            float x0 = chunk[cl * 64 + pq * 4 + 0];
            float x1 = chunk[cl * 64 + pq * 4 + 1];
            float x2 = chunk[cl * 64 + pq * 4 + 2];
            float x3 = chunk[cl * 64 + pq * 4 + 3];
            #pragma unroll
            for (int k = 0; k < 4; ++k) {
                float w = dsw[(4 * oq + k) * CIN + c];
                acc[k][0] = fmaf(w, x0, acc[k][0]);
                acc[k][1] = fmaf(w, x1, acc[k][1]);
                acc[k][2] = fmaf(w, x2, acc[k][2]);
                acc[k][3] = fmaf(w, x3, acc[k][3]);
            }
        }
    }

    float s4[4], cb4[4];
    #pragma unroll
    for (int k = 0; k < 4; ++k) {
        int o = 4 * oq + k;
        s4[k]  = g2[o] / sqrtf(v2[o] + EPSV);
        cb4[k] = dsb[o] * s4[k] + b2[o] - m2[o] * s4[k];
    }
    #pragma unroll
    for (int j = 0; j < 4; ++j) {
        u16x4 v;
        #pragma unroll
        for (int k = 0; k < 4; ++k)
            v[k] = f2bf(fmaxf(0.f, fmaf(acc[k][j], s4[k], cb4[k])));
        *(u16x4*)&out[(size_t)(pos0 + pq * 4 + j) * 64 + 4 * oq] = v;
    }
}

// ---------------------------------------------------------------------------
// conv3a: bf16 MFMA implicit GEMM + BN + ReLU -> y1t [d][h][w][o] bf16.
// Split slabs: Lsl staged once per kh (d-mask applied per-lane at MFMA);
// Rsl double-buffered, staged per (kd,kh) with the mask folded into bounds.
// One barrier per R phase; scalar skip of fully-masked n-tiles.
// ---------------------------------------------------------------------------
__global__ __launch_bounds__(256) void CostVolume_6201932775918_c3a(
    const unsigned short* Lt, const unsigned short* Rt,
    const unsigned short* Wb,
    const float* cb3, const float* g3, const float* b3,
    const float* m3, const float* v3,
    unsigned short* y1t)
{
    const int h    = (int)blockIdx.x;
    const int d    = (int)blockIdx.y;
    const int t    = (int)threadIdx.x;
    const int wave = t >> 6;
    const int lane = t & 63;
    const int l15  = lane & 15;
    const int lhi  = lane >> 4;

    __shared__ __align__(16) unsigned short Lsl[WSLAB * 64];      // 20736 B
    __shared__ __align__(16) unsigned short Rsl[2][WSLAB * 64];   // 41472 B

    f32x4 acc[10];
    #pragma unroll
    for (int n = 0; n < 10; ++n) acc[n] = (f32x4){0.f, 0.f, 0.f, 0.f};

    char* LB = (char*)Lsl;
    int buf = 0;

    for (int kh = 0; kh < 3; ++kh) {
        const int hp = h + kh - 1;
        if (hp < 0 || hp >= HH) continue;
        __syncthreads();                         // protect Lsl from prior reads
        // ---- stage L (bounds only; d-mask applied at MFMA) ----
        const unsigned short* Lrow = Lt + (size_t)hp * WW * 64;
        #pragma unroll
        for (int i = 0; i < 6; ++i) {
            int e = i * 256 + t;
            if (e < WSLAB * 8) {
                int wIdx = e >> 3, c8 = e & 7, wp = wIdx - 1;
                u16x4 v0 = (u16x4){0, 0, 0, 0}, v1 = (u16x4){0, 0, 0, 0};
                if (wp >= 0 && wp < WW) {
                    const unsigned short* src = Lrow + (size_t)wp * 64 + c8 * 8;
                    v0 = *(const u16x4*)src;
                    v1 = *(const u16x4*)(src + 4);
                }
                int byte = (wIdx * 128 + c8 * 16) ^ ((wIdx & 7) << 4);
                *(u16x4*)(LB + byte)     = v0;
                *(u16x4*)(LB + byte + 8) = v1;
            }
        }
        const unsigned short* Rrow = Rt + (size_t)hp * WW * 64;
        for (int kd = 0; kd < 3; ++kd) {
            const int dp = d + kd - 1;
            if (dp < 0 || dp >= DDN) continue;
            char* RB = (char*)Rsl[buf];
            // ---- stage R[buf]: mask wp>=dp folds into index bounds ----
            #pragma unroll
            for (int i = 0; i < 6; ++i) {
                int e = i * 256 + t;
                if (e < WSLAB * 8) {
                    int wIdx = e >> 3, c8 = e & 7, wp = wIdx - 1;
                    u16x4 v0 = (u16x4){0, 0, 0, 0}, v1 = (u16x4){0, 0, 0, 0};
                    if (wp >= dp && wp < WW) {
                        const unsigned short* src =
                            Rrow + (size_t)(wp - dp) * 64 + c8 * 8;
                        v0 = *(const u16x4*)src;
                        v1 = *(const u16x4*)(src + 4);
                    }
                    int byte = (wIdx * 128 + c8 * 16) ^ ((wIdx & 7) << 4);
                    *(u16x4*)(RB + byte)     = v0;
                    *(u16x4*)(RB + byte + 8) = v1;
                }
            }
            __syncthreads();
            // ---- MFMA: 3 kw x (2 L-chunks + 2 R-chunks) x 10 n-tiles ----
            const int tap0 = (kd * 3 + kh) * 3;
            #pragma unroll
            for (int kw = 0; kw < 3; ++kw) {
                const unsigned short* wrow =
                    Wb + (16 * wave + l15) * (NTAP * 128) + (tap0 + kw) * 128 + lhi * 8;
                #pragma unroll
                for (int kc = 0; kc < 4; ++kc) {
                    bf16x8 afrag = *(const bf16x8*)(wrow + kc * 32);
                    const bool isL = (kc < 2);
                    const int ci2 = ((isL ? kc : kc - 2) * 32 + lhi * 8) * 2;
                    const char* base = isL ? LB : RB;
                    #pragma unroll
                    for (int n = 0; n < 10; ++n) {
                        if (16 * n + 14 + kw >= dp) {      // tile has unmasked lanes
                            int wIdx = 16 * n + l15 + kw;
                            int byte = (wIdx * 128 + ci2) ^ ((wIdx & 7) << 4);
                            bf16x8 b = *(const bf16x8*)(base + byte);
                            if (isL && wIdx < dp + 1)      // per-lane d-mask (L only)
                                b = (bf16x8){0, 0, 0, 0, 0, 0, 0, 0};
                            acc[n] = __builtin_amdgcn_mfma_f32_16x16x32_bf16(
                                afrag, b, acc[n], 0, 0, 0);
                        }
                    }
                }
            }
            buf ^= 1;
        }
    }

    float s4[4], cb4[4];
    #pragma unroll
    for (int r = 0; r < 4; ++r) {
        const int o = 16 * wave + lhi * 4 + r;
        s4[r]  = g3[o] / sqrtf(v3[o] + EPSV);
        cb4[r] = cb3[o] * s4[r] + b3[o] - m3[o] * s4[r];
    }
    unsigned short* ybase =
        y1t + ((size_t)(d * HH + h) * WW) * 64 + 16 * wave + lhi * 4;
    #pragma unroll
    for (int n = 0; n < 10; ++n) {
        int w = 16 * n + l15;
        u16x4 v;
        #pragma unroll
        for (int r = 0; r < 4; ++r)
            v[r] = f2bf(fmaxf(0.f, fmaf(acc[n][r], s4[r], cb4[r])));
        *(u16x4*)(ybase + (size_t)w * 64) = v;
    }
}

// ---------------------------------------------------------------------------
// conv3b: bf16 MFMA implicit GEMM, DOUBLE-BUFFERED slab (1 barrier/phase).
// K = 64 ci x 27 taps. Output f32 ((o*D+d)*H+h)*W + w.
// ---------------------------------------------------------------------------
__global__ __launch_bounds__(256) void CostVolume_6201932775918_c3b(
    const unsigned short* y1t, const unsigned short* Wb2,
    const float* cb3, const float* g3, const float* b3,
    const float* m3, const float* v3,
    float* outp)
{
    const int h    = (int)blockIdx.x;
    const int d    = (int)blockIdx.y;
    const int t    = (int)threadIdx.x;
    const int wave = t >> 6;
    const int lane = t & 63;
    const int l15  = lane & 15;
    const int lhi  = lane >> 4;

    __shared__ __align__(16) unsigned short S[2][WSLAB * 64];    // 41472 B

    f32x4 acc[10];
    #pragma unroll
    for (int n = 0; n < 10; ++n) acc[n] = (f32x4){0.f, 0.f, 0.f, 0.f};

    int buf = 0;

    for (int kd = 0; kd < 3; ++kd) {
        const int dp = d + kd - 1;
        if (dp < 0 || dp >= DDN) continue;
        for (int kh = 0; kh < 3; ++kh) {
            const int hp = h + kh - 1;
            if (hp < 0 || hp >= HH) continue;
            char* SB = (char*)S[buf];
            const unsigned short* yrow = y1t + ((size_t)(dp * HH + hp) * WW) * 64;
            #pragma unroll
            for (int i = 0; i < 6; ++i) {
                int e = i * 256 + t;
                if (e < WSLAB * 8) {
                    int wIdx = e >> 3, c8 = e & 7, wp = wIdx - 1;
                    u16x4 v0 = (u16x4){0, 0, 0, 0}, v1 = (u16x4){0, 0, 0, 0};
                    if (wp >= 0 && wp < WW) {
                        const unsigned short* src = yrow + (size_t)wp * 64 + c8 * 8;
                        v0 = *(const u16x4*)src;
                        v1 = *(const u16x4*)(src + 4);
                    }
                    int byte = (wIdx * 128 + c8 * 16) ^ ((wIdx & 7) << 4);
                    *(u16x4*)(SB + byte)     = v0;
                    *(u16x4*)(SB + byte + 8) = v1;
                }
            }
            __syncthreads();
            const int tap0 = (kd * 3 + kh) * 3;
            #pragma unroll
            for (int kw = 0; kw < 3; ++kw) {
                const unsigned short* wrow =
                    Wb2 + (16 * wave + l15) * (NTAP * 64) + (tap0 + kw) * 64 + lhi * 8;
                #pragma unroll
                for (int kc = 0; kc < 2; ++kc) {
                    bf16x8 afrag = *(const bf16x8*)(wrow + kc * 32);
                    const int ci2 = (kc * 32 + lhi * 8) * 2;
                    #pragma unroll
                    for (int n = 0; n < 10; ++n) {
                        int wIdx = 16 * n + l15 + kw;
                        int byte = (wIdx * 128 + ci2) ^ ((wIdx & 7) << 4);
                        bf16x8 b = *(const bf16x8*)(SB + byte);
                        acc[n] = __builtin_amdgcn_mfma_f32_16x16x32_bf16(
                            afrag, b, acc[n], 0, 0, 0);
                    }
                }
            }
            buf ^= 1;
        }
    }

    float s4[4], cb4[4];
    #pragma unroll
    for (int r = 0; r < 4; ++r) {
        const int o = 16 * wave + lhi * 4 + r;
        s4[r]  = g3[o] / sqrtf(v3[o] + EPSV);
        cb4[r] = cb3[o] * s4[r] + b3[o] - m3[o] * s4[r];
    }
    #pragma unroll
    for (int r = 0; r < 4; ++r) {
        const int o = 16 * wave + lhi * 4 + r;
        float* orow = outp + ((size_t)(o * DDN + d) * HH + h) * WW;
        #pragma unroll
        for (int n = 0; n < 10; ++n) {
            int w = 16 * n + l15;
            orow[w] = fmaxf(0.f, fmaf(acc[n][r], s4[r], cb4[r]));
        }
    }
}

// ---------------------------------------------------------------------------
extern "C" void kernel_launch(void* const* d_in, const int* in_sizes, int n_in,
                              void* d_out, int out_size, void* d_ws, size_t ws_size,
                              hipStream_t stream)
{
    (void)in_sizes; (void)n_in; (void)out_size;

    const float* Lf  = (const float*)d_in[0];
    const float* Rf  = (const float*)d_in[1];
    const float* dsw = (const float*)d_in[2];
    const float* dsb = (const float*)d_in[3];
    const float* g2  = (const float*)d_in[4];
    const float* b2  = (const float*)d_in[5];
    const float* m2  = (const float*)d_in[6];
    const float* v2  = (const float*)d_in[7];
    const float* w3a = (const float*)d_in[8];
    const float* cba = (const float*)d_in[9];
    const float* g3a = (const float*)d_in[10];
    const float* b3a = (const float*)d_in[11];
    const float* m3a = (const float*)d_in[12];
    const float* v3a = (const float*)d_in[13];
    const float* w3b = (const float*)d_in[14];
    const float* cbb = (const float*)d_in[15];
    const float* g3b = (const float*)d_in[16];
    const float* b3b = (const float*)d_in[17];
    const float* m3b = (const float*)d_in[18];
    const float* v3b = (const float*)d_in[19];

    float* outF = (float*)d_out;       // output dtype: FLOAT32

    unsigned short* Lt  = (unsigned short*)d_ws;
    unsigned short* Rt  = (unsigned short*)((char*)d_ws + 983040);
    unsigned short* Wb  = (unsigned short*)((char*)d_ws + 1966080);
    unsigned short* Wb2 = (unsigned short*)((char*)d_ws + 2408448);
    unsigned short* y1t = (unsigned short*)((char*)d_ws + 2629632);
    if (ws_size < 2629632 + (size_t)DDN * HH * WW * 64 * 2) return;

    CostVolume_6201932775918_packw<<<dim3(864), 256, 0, stream>>>(w3a, Wb);
    CostVolume_6201932775918_packw2<<<dim3(432), 256, 0, stream>>>(w3b, Wb2);

    CostVolume_6201932775918_ds<<<dim3(120, 2), 256, 0, stream>>>(
        Lf, Rf, dsw, dsb, g2, b2, m2, v2, Lt, Rt);

    CostVolume_6201932775918_c3a<<<dim3(48, 48), 256, 0, stream>>>(
        Lt, Rt, Wb, cba, g3a, b3a, m3a, v3a, y1t);

    CostVolume_6201932775918_c3b<<<dim3(48, 48), 256, 0, stream>>>(
        y1t, Wb2, cbb, g3b, b3b, m3b, v3b, outF);
}